// Round 1
// baseline (8895.288 us; speedup 1.0000x reference)
//
#include <hip/hip_runtime.h>

#define T_STEPS 8192
#define BATCH   128
#define HID     128

// tanh(z) = sign(z) * (1 - e^{-2|z|}) / (1 + e^{-2|z|})  -- no overflow path
__device__ __forceinline__ float fast_tanh(float z) {
    float az = fabsf(z);
    float e  = __expf(-2.0f * az);
    float r  = __fdividef(1.0f - e, 1.0f + e);
    return copysignf(r, z);
}

__global__ __launch_bounds__(HID) void odenet_scan(
    const float* __restrict__ x,
    const float* __restrict__ W1, const float* __restrict__ b1,
    const float* __restrict__ W2, const float* __restrict__ b2,
    const float* __restrict__ W3, const float* __restrict__ b3,
    float* __restrict__ out) {

    const int b = blockIdx.x;      // batch element
    const int j = threadIdx.x;     // hidden unit owned by this thread

    __shared__ __align__(16) float h1buf[HID];
    __shared__ float red[2];

    // ---- loop-invariant weights -> registers ----
    float w2col[HID];              // W2[:, j]
    #pragma unroll
    for (int k = 0; k < HID; ++k) w2col[k] = W2[k * HID + j];
    const float w10 = W1[j];           // W1[0][j]
    const float w11 = W1[HID + j];     // W1[1][j]
    const float b1j = b1[j];
    const float b2j = b2[j];
    const float w3j = W3[j];
    const float b3v = b3[0];

    const int lane = j & 63;
    const int wid  = j >> 6;

    float y = 0.0f;
    if (j == 0) out[b] = 0.0f;         // y_0 = 0

    float xv = x[b];                   // x_0, prefetched

    for (int t = 0; t < T_STEPS - 1; ++t) {
        // prefetch next step's x (wave-uniform address -> scalar load)
        float xn = x[(t + 1) * BATCH + b];

        // ---- layer 1: h1[j] = tanh(x*W1[0,j] + y*W1[1,j] + b1[j]) ----
        float h1j = fast_tanh(fmaf(xv, w10, fmaf(y, w11, b1j)));
        h1buf[j] = h1j;
        __syncthreads();

        // ---- layer 2: h2[j] = tanh(dot(h1, W2[:,j]) + b2[j]) ----
        float a0 = 0.f, a1 = 0.f, a2 = 0.f, a3 = 0.f;
        const float4* h4 = (const float4*)h1buf;
        #pragma unroll
        for (int k4 = 0; k4 < HID / 4; ++k4) {
            float4 h = h4[k4];         // broadcast ds_read_b128
            a0 = fmaf(w2col[4 * k4 + 0], h.x, a0);
            a1 = fmaf(w2col[4 * k4 + 1], h.y, a1);
            a2 = fmaf(w2col[4 * k4 + 2], h.z, a2);
            a3 = fmaf(w2col[4 * k4 + 3], h.w, a3);
        }
        float h2j = fast_tanh(((a0 + a1) + (a2 + a3)) + b2j);

        // ---- layer 3 + reduction: dy = sum_j W3[j]*h2[j] + b3 ----
        float p = w3j * h2j;
        #pragma unroll
        for (int off = 32; off; off >>= 1) p += __shfl_xor(p, off, 64);
        if (lane == 0) red[wid] = p;
        __syncthreads();

        y += (red[0] + red[1]) + b3v;  // DT = 1.0
        if (j == 0) out[(t + 1) * BATCH + b] = y;

        xv = xn;
    }
}

extern "C" void kernel_launch(void* const* d_in, const int* in_sizes, int n_in,
                              void* d_out, int out_size, void* d_ws, size_t ws_size,
                              hipStream_t stream) {
    const float* x  = (const float*)d_in[0];
    const float* W1 = (const float*)d_in[1];
    const float* b1 = (const float*)d_in[2];
    const float* W2 = (const float*)d_in[3];
    const float* b2 = (const float*)d_in[4];
    const float* W3 = (const float*)d_in[5];
    const float* b3 = (const float*)d_in[6];

    odenet_scan<<<dim3(BATCH), dim3(HID), 0, stream>>>(
        x, W1, b1, W2, b2, W3, b3, (float*)d_out);
}

// Round 2
// 7069.991 us; speedup vs baseline: 1.2582x; 1.2582x over previous
//
#include <hip/hip_runtime.h>

#define T_STEPS 8192
#define BATCH   128
#define HID     128
#define SPLIT   4
#define CHUNK   (HID / SPLIT)     // 32 floats of W2 column per thread
#define NTHR    (HID * SPLIT)     // 512 threads = 8 waves

// tanh(z) = sign(z) * (1 - e^{-2|z|}) / (1 + e^{-2|z|})  -- no overflow path
__device__ __forceinline__ float fast_tanh(float z) {
    float az = fabsf(z);
    float e  = __expf(-2.0f * az);
    float r  = __fdividef(1.0f - e, 1.0f + e);
    return copysignf(r, z);
}

__global__ __launch_bounds__(NTHR) void odenet_scan(
    const float* __restrict__ x,
    const float* __restrict__ W1, const float* __restrict__ b1,
    const float* __restrict__ W2, const float* __restrict__ b2,
    const float* __restrict__ W3, const float* __restrict__ b3,
    float* __restrict__ out) {

    const int b    = blockIdx.x;       // batch element
    const int tid  = threadIdx.x;
    const int s    = tid >> 7;         // k-split index 0..3 (wave-uniform)
    const int j    = tid & (HID - 1);  // hidden unit 0..127
    const int lane = tid & 63;

    __shared__ __align__(16) float h1buf[HID];
    __shared__ __align__(16) float pbuf[NTHR];   // layout [j*4 + s]

    // ---- W2 fragment: rows [CHUNK*s, CHUNK*(s+1)) of column j ----
    // 8 x float4 = 128 B/thread -> register-resident (round-1 failure mode:
    // 512 B array stayed in scratch, VGPR_Count=84 proved it)
    float4 w2f[CHUNK / 4];
    #pragma unroll
    for (int i = 0; i < CHUNK / 4; ++i) {
        const int k = CHUNK * s + 4 * i;
        w2f[i] = make_float4(W2[(k + 0) * HID + j], W2[(k + 1) * HID + j],
                             W2[(k + 2) * HID + j], W2[(k + 3) * HID + j]);
    }
    const float w10 = W1[j], w11 = W1[HID + j], b1j = b1[j];
    const float b2a = b2[lane], b2b = b2[lane + 64];
    const float w3a = W3[lane], w3b = W3[lane + 64];
    const float b3v = b3[0];

    float y = 0.0f;
    if (tid == 0) out[b] = 0.0f;       // y_0 = 0
    float xv = x[b];

    for (int t = 0; t < T_STEPS - 1; ++t) {
        float xn = x[(t + 1) * BATCH + b];   // block-uniform -> scalar load

        // ---- layer 1 (waves 0-1 only): h1[j] = tanh(x*W1[0,j] + y*W1[1,j] + b1[j])
        if (s == 0)
            h1buf[j] = fast_tanh(fmaf(xv, w10, fmaf(y, w11, b1j)));
        __syncthreads();   // h1 ready; also separates prev C-reads from B-writes of pbuf

        // ---- layer 2 partial: p = sum_{k in chunk} h1[k] * W2[k][j]
        // h1 reads: wave-uniform address (s uniform per wave) -> pure LDS broadcast
        const float4* h4 = (const float4*)h1buf;
        float a0 = 0.f, a1 = 0.f, a2 = 0.f, a3 = 0.f;
        #pragma unroll
        for (int i = 0; i < CHUNK / 4; ++i) {
            float4 h = h4[s * (CHUNK / 4) + i];
            a0 = fmaf(w2f[i].x, h.x, a0);
            a1 = fmaf(w2f[i].y, h.y, a1);
            a2 = fmaf(w2f[i].z, h.z, a2);
            a3 = fmaf(w2f[i].w, h.w, a3);
        }
        pbuf[(j << 2) | s] = (a0 + a1) + (a2 + a3);
        __syncthreads();   // partials ready

        // ---- layer 2 combine + layer 3 + reduce, replicated in EVERY wave so
        // y broadcasts without a third barrier. Lane l handles units l and l+64.
        const float4* p4 = (const float4*)pbuf;
        float4 pa = p4[lane];
        float4 pb = p4[lane + 64];
        float ca = w3a * fast_tanh((pa.x + pa.y) + (pa.z + pa.w) + b2a);
        float cb = w3b * fast_tanh((pb.x + pb.y) + (pb.z + pb.w) + b2b);
        float c = ca + cb;
        #pragma unroll
        for (int off = 32; off; off >>= 1) c += __shfl_xor(c, off, 64);

        y += c + b3v;      // DT = 1.0; identical in all waves
        if (tid == 0) out[(t + 1) * BATCH + b] = y;
        xv = xn;
    }
}

extern "C" void kernel_launch(void* const* d_in, const int* in_sizes, int n_in,
                              void* d_out, int out_size, void* d_ws, size_t ws_size,
                              hipStream_t stream) {
    const float* x  = (const float*)d_in[0];
    const float* W1 = (const float*)d_in[1];
    const float* b1 = (const float*)d_in[2];
    const float* W2 = (const float*)d_in[3];
    const float* b2 = (const float*)d_in[4];
    const float* W3 = (const float*)d_in[5];
    const float* b3 = (const float*)d_in[6];

    odenet_scan<<<dim3(BATCH), dim3(NTHR), 0, stream>>>(
        x, W1, b1, W2, b2, W3, b3, (float*)d_out);
}

// Round 3
// 6101.960 us; speedup vs baseline: 1.4578x; 1.1586x over previous
//
#include <hip/hip_runtime.h>

#define T_STEPS 8192
#define BATCH   128
#define HID     128
#define SPLIT   4
#define CHUNK   (HID / SPLIT)     // 32 floats of W2 column per thread
#define NTHR    (HID * SPLIT)     // 512 threads = 8 waves

// tanh(z) = sign(z) * (1 - e^{-2|z|}) / (1 + e^{-2|z|})  -- no overflow path
__device__ __forceinline__ float fast_tanh(float z) {
    float az = fabsf(z);
    float e  = __expf(-2.0f * az);
    float r  = __fdividef(1.0f - e, 1.0f + e);
    return copysignf(r, z);
}

// wave64 sum via DPP (VALU-only, ~6 dependent adds), result broadcast from lane 63.
// t = dpp_mov(0, x, ctrl): lanes outside the pattern get old=0, so "+= t" is safe.
__device__ __forceinline__ float wave64_sum(float x) {
#define DPP_ADD(ctrl) do {                                                        \
        int t_ = __builtin_amdgcn_update_dpp(0, __builtin_bit_cast(int, x),       \
                                             (ctrl), 0xf, 0xf, false);            \
        x += __builtin_bit_cast(float, t_); } while (0)
    DPP_ADD(0x111);  // row_shr:1
    DPP_ADD(0x112);  // row_shr:2
    DPP_ADD(0x114);  // row_shr:4
    DPP_ADD(0x118);  // row_shr:8  -> lane 15/31/47/63 hold row sums
    DPP_ADD(0x142);  // row_bcast:15 -> lane 31, 63 hold half sums
    DPP_ADD(0x143);  // row_bcast:31 -> lane 63 holds full sum
#undef DPP_ADD
    int s_ = __builtin_amdgcn_readlane(__builtin_bit_cast(int, x), 63);
    return __builtin_bit_cast(float, s_);
}

// launch_bounds(512, 2): 2 waves/EU min -> VGPR cap 256 (not 64!). Rounds 1-2
// spilled the W2 fragment because the default occupancy target capped VGPRs.
__global__ __launch_bounds__(NTHR, 2) void odenet_scan(
    const float* __restrict__ x,
    const float* __restrict__ W1, const float* __restrict__ b1,
    const float* __restrict__ W2, const float* __restrict__ b2,
    const float* __restrict__ W3, const float* __restrict__ b3,
    float* __restrict__ out) {

    const int b    = blockIdx.x;       // batch element
    const int tid  = threadIdx.x;
    const int s    = tid >> 7;         // k-split index 0..3 (wave-uniform)
    const int j    = tid & (HID - 1);  // hidden unit 0..127
    const int lane = tid & 63;

    __shared__ __align__(16) float h1buf[HID];
    __shared__ __align__(16) float pbuf[NTHR];   // layout [s*HID + j] (conflict-free)

    // ---- W2 fragment: rows [CHUNK*s, CHUNK*(s+1)) of column j ----
    // 8 NAMED float4 locals (SSA values, not an alloca) -> register-resident.
    const float* col = W2 + j;         // column j, row stride HID
    const int kb = CHUNK * s;
#define LOADW(k) make_float4(col[(k) * HID], col[(k + 1) * HID],                  \
                             col[(k + 2) * HID], col[(k + 3) * HID])
    const float4 wf0 = LOADW(kb + 0),  wf1 = LOADW(kb + 4);
    const float4 wf2 = LOADW(kb + 8),  wf3 = LOADW(kb + 12);
    const float4 wf4 = LOADW(kb + 16), wf5 = LOADW(kb + 20);
    const float4 wf6 = LOADW(kb + 24), wf7 = LOADW(kb + 28);
#undef LOADW

    const float w10 = W1[j], w11 = W1[HID + j], b1j = b1[j];
    const float b2a = b2[lane], b2b = b2[lane + 64];
    const float w3a = W3[lane], w3b = W3[lane + 64];
    const float b3v = b3[0];

    float y  = 0.0f;
    float xv = x[b];                   // x_0
    if (tid == 0) out[b] = 0.0f;       // y_0 = 0

    for (int t = 0; t < T_STEPS - 1; ++t) {
        // ---- phase A (waves 0-1 only): h1[j] = tanh(x*W1[0,j] + y*W1[1,j] + b1[j])
        float xn = 0.0f;
        if (s == 0) {
            xn = x[(t + 1) * BATCH + b];            // prefetch next x (uniform)
            h1buf[j] = fast_tanh(fmaf(xv, w10, fmaf(y, w11, b1j)));
        }
        __syncthreads();   // h1 ready; also orders prev C-reads before B-writes

        // ---- phase B (all 8 waves): partial dot, h1 via wave-uniform broadcast
        const float4* h4 = (const float4*)h1buf + s * (CHUNK / 4);
        float a0 = 0.f, a1 = 0.f, a2 = 0.f, a3 = 0.f;
        float4 h;
#define FMA4(W, idx) h = h4[idx];                                                 \
        a0 = fmaf((W).x, h.x, a0); a1 = fmaf((W).y, h.y, a1);                     \
        a2 = fmaf((W).z, h.z, a2); a3 = fmaf((W).w, h.w, a3)
        FMA4(wf0, 0); FMA4(wf1, 1); FMA4(wf2, 2); FMA4(wf3, 3);
        FMA4(wf4, 4); FMA4(wf5, 5); FMA4(wf6, 6); FMA4(wf7, 7);
#undef FMA4
        pbuf[s * HID + j] = (a0 + a1) + (a2 + a3);
        __syncthreads();   // partials ready

        // ---- phase C (waves 0-1 only; each wave covers all 128 units itself,
        // so both compute the identical dy -- no cross-wave combine needed)
        if (s == 0) {
            float sa = pbuf[0 * HID + lane]      + pbuf[1 * HID + lane]
                     + pbuf[2 * HID + lane]      + pbuf[3 * HID + lane];
            float sb = pbuf[0 * HID + lane + 64] + pbuf[1 * HID + lane + 64]
                     + pbuf[2 * HID + lane + 64] + pbuf[3 * HID + lane + 64];
            float c = fmaf(w3a, fast_tanh(sa + b2a), w3b * fast_tanh(sb + b2b));
            y += wave64_sum(c) + b3v;               // DT = 1.0
            if (tid == 0) out[(t + 1) * BATCH + b] = y;
            xv = xn;
        }
    }
}

extern "C" void kernel_launch(void* const* d_in, const int* in_sizes, int n_in,
                              void* d_out, int out_size, void* d_ws, size_t ws_size,
                              hipStream_t stream) {
    const float* x  = (const float*)d_in[0];
    const float* W1 = (const float*)d_in[1];
    const float* b1 = (const float*)d_in[2];
    const float* W2 = (const float*)d_in[3];
    const float* b2 = (const float*)d_in[4];
    const float* W3 = (const float*)d_in[5];
    const float* b3 = (const float*)d_in[6];

    odenet_scan<<<dim3(BATCH), dim3(NTHR), 0, stream>>>(
        x, W1, b1, W2, b2, W3, b3, (float*)d_out);
}

// Round 4
// 6047.544 us; speedup vs baseline: 1.4709x; 1.0090x over previous
//
#include <hip/hip_runtime.h>

#define T_STEPS 8192
#define BATCH   128
#define HID     128
#define SPLIT   4
#define CHUNK   (HID / SPLIT)     // 32 floats of W2 column per thread
#define NTHR    (HID * SPLIT)     // 512 threads = 8 waves

// tanh(z) = sign(z) * (1 - e^{-2|z|}) / (1 + e^{-2|z|})  -- no overflow path
__device__ __forceinline__ float fast_tanh(float z) {
    float az = fabsf(z);
    float e  = __expf(-2.0f * az);
    float r  = __fdividef(1.0f - e, 1.0f + e);
    return copysignf(r, z);
}

// wave64 sum via DPP (VALU-only, ~6 dependent adds), result broadcast from lane 63.
__device__ __forceinline__ float wave64_sum(float x) {
#define DPP_ADD(ctrl) do {                                                        \
        int t_ = __builtin_amdgcn_update_dpp(0, __builtin_bit_cast(int, x),       \
                                             (ctrl), 0xf, 0xf, false);            \
        x += __builtin_bit_cast(float, t_); } while (0)
    DPP_ADD(0x111);  // row_shr:1
    DPP_ADD(0x112);  // row_shr:2
    DPP_ADD(0x114);  // row_shr:4
    DPP_ADD(0x118);  // row_shr:8  -> lane 15/31/47/63 hold row sums
    DPP_ADD(0x142);  // row_bcast:15 -> lanes 31, 63 hold half sums
    DPP_ADD(0x143);  // row_bcast:31 -> lane 63 holds full sum
#undef DPP_ADD
    int s_ = __builtin_amdgcn_readlane(__builtin_bit_cast(int, x), 63);
    return __builtin_bit_cast(float, s_);
}

__global__ __launch_bounds__(NTHR, 2) void odenet_scan(
    const float* __restrict__ x,
    const float* __restrict__ W1, const float* __restrict__ b1,
    const float* __restrict__ W2, const float* __restrict__ b2,
    const float* __restrict__ W3, const float* __restrict__ b3,
    float* __restrict__ out) {

    const int b    = blockIdx.x;       // batch element
    const int tid  = threadIdx.x;
    const int s    = tid >> 7;         // k-split index 0..3 (wave-uniform)
    const int j    = tid & (HID - 1);  // hidden unit 0..127
    const int lane = tid & 63;

    __shared__ __align__(16) float h1buf[HID];
    __shared__ __align__(16) float pbuf[NTHR];   // layout [s*HID + j] (conflict-free)

    // ---- W2 fragment: rows [CHUNK*s, CHUNK*(s+1)) of column j, 32 scalars ----
    // R1-R3 failure: __syncthreads' fence makes these loads "re-loadable", and
    // the compiler re-issued all 32 global loads EVERY step (VGPR_Count stuck
    // at 36). The empty asm below makes each value opaque: it cannot be
    // rematerialized from memory and must stay resident in a VGPR.
    const float* col = W2 + j;         // column j, row stride HID
    const int kb = CHUNK * s;
#define LW(k) col[(kb + (k)) * HID]
    float w00 = LW( 0), w01 = LW( 1), w02 = LW( 2), w03 = LW( 3);
    float w04 = LW( 4), w05 = LW( 5), w06 = LW( 6), w07 = LW( 7);
    float w08 = LW( 8), w09 = LW( 9), w10_ = LW(10), w11_ = LW(11);
    float w12 = LW(12), w13 = LW(13), w14 = LW(14), w15 = LW(15);
    float w16 = LW(16), w17 = LW(17), w18 = LW(18), w19 = LW(19);
    float w20 = LW(20), w21 = LW(21), w22 = LW(22), w23 = LW(23);
    float w24 = LW(24), w25 = LW(25), w26 = LW(26), w27 = LW(27);
    float w28 = LW(28), w29 = LW(29), w30 = LW(30), w31 = LW(31);
#undef LW
    float w10 = W1[j], w11 = W1[HID + j], b1j = b1[j];
    float b2a = b2[lane], b2b = b2[lane + 64];
    float w3a = W3[lane], w3b = W3[lane + 64];
    float b3v = b3[0];

#define PIN8(a,b_,c,d,e,f,g,h) asm volatile("" : "+v"(a),"+v"(b_),"+v"(c),      \
        "+v"(d),"+v"(e),"+v"(f),"+v"(g),"+v"(h))
    PIN8(w00, w01, w02, w03, w04, w05, w06, w07);
    PIN8(w08, w09, w10_, w11_, w12, w13, w14, w15);
    PIN8(w16, w17, w18, w19, w20, w21, w22, w23);
    PIN8(w24, w25, w26, w27, w28, w29, w30, w31);
    PIN8(w10, w11, b1j, b2a, b2b, w3a, w3b, b3v);
#undef PIN8

    float y  = 0.0f;
    float xv = x[b];                   // x_0
    if (tid == 0) out[b] = 0.0f;       // y_0 = 0

    for (int t = 0; t < T_STEPS - 1; ++t) {
        // ---- phase A (waves 0-1 only): h1[j] = tanh(x*W1[0,j] + y*W1[1,j] + b1[j])
        float xn = 0.0f;
        if (s == 0) {
            xn = x[(t + 1) * BATCH + b];            // prefetch next x (uniform)
            h1buf[j] = fast_tanh(fmaf(xv, w10, fmaf(y, w11, b1j)));
        }
        __syncthreads();   // h1 ready; also orders prev C-reads before B-writes

        // ---- phase B (all 8 waves): partial dot, h1 via wave-uniform broadcast
        const float4* h4 = (const float4*)h1buf + s * (CHUNK / 4);
        float a0 = 0.f, a1 = 0.f, a2 = 0.f, a3 = 0.f;
        float4 h;
#define FMA4(wa, wb, wc, wd, idx) h = h4[idx];                                    \
        a0 = fmaf((wa), h.x, a0); a1 = fmaf((wb), h.y, a1);                       \
        a2 = fmaf((wc), h.z, a2); a3 = fmaf((wd), h.w, a3)
        FMA4(w00, w01, w02, w03, 0); FMA4(w04, w05, w06, w07, 1);
        FMA4(w08, w09, w10_, w11_, 2); FMA4(w12, w13, w14, w15, 3);
        FMA4(w16, w17, w18, w19, 4); FMA4(w20, w21, w22, w23, 5);
        FMA4(w24, w25, w26, w27, 6); FMA4(w28, w29, w30, w31, 7);
#undef FMA4
        pbuf[s * HID + j] = (a0 + a1) + (a2 + a3);
        __syncthreads();   // partials ready

        // ---- phase C (waves 0-1 only; each wave covers all 128 units itself,
        // so both compute the identical dy -- no cross-wave combine needed)
        if (s == 0) {
            float sa = pbuf[0 * HID + lane]      + pbuf[1 * HID + lane]
                     + pbuf[2 * HID + lane]      + pbuf[3 * HID + lane];
            float sb = pbuf[0 * HID + lane + 64] + pbuf[1 * HID + lane + 64]
                     + pbuf[2 * HID + lane + 64] + pbuf[3 * HID + lane + 64];
            float c = fmaf(w3a, fast_tanh(sa + b2a), w3b * fast_tanh(sb + b2b));
            y += wave64_sum(c) + b3v;               // DT = 1.0
            if (tid == 0) out[(t + 1) * BATCH + b] = y;
            xv = xn;
        }
    }
}

extern "C" void kernel_launch(void* const* d_in, const int* in_sizes, int n_in,
                              void* d_out, int out_size, void* d_ws, size_t ws_size,
                              hipStream_t stream) {
    const float* x  = (const float*)d_in[0];
    const float* W1 = (const float*)d_in[1];
    const float* b1 = (const float*)d_in[2];
    const float* W2 = (const float*)d_in[3];
    const float* b2 = (const float*)d_in[4];
    const float* W3 = (const float*)d_in[5];
    const float* b3 = (const float*)d_in[6];

    odenet_scan<<<dim3(BATCH), dim3(NTHR), 0, stream>>>(
        x, W1, b1, W2, b2, W3, b3, (float*)d_out);
}

// Round 5
// 5143.145 us; speedup vs baseline: 1.7295x; 1.1758x over previous
//
#include <hip/hip_runtime.h>

#define T_STEPS 8192
#define BATCH   128
#define HID     128
#define SPLIT   4
#define CHUNK   (HID / SPLIT)     // 32 floats of W2 column per thread
#define NTHR    (HID * SPLIT)     // 512 threads = 8 waves

// tanh(z) = sign(z) * (1 - e^{-2|z|}) / (1 + e^{-2|z|})  -- no overflow path
__device__ __forceinline__ float fast_tanh(float z) {
    float az = fabsf(z);
    float e  = __expf(-2.0f * az);
    float r  = __fdividef(1.0f - e, 1.0f + e);
    return copysignf(r, z);
}

// wave64 sum via DPP (VALU-only, ~6 dependent adds), result broadcast from lane 63.
__device__ __forceinline__ float wave64_sum(float x) {
#define DPP_ADD(ctrl) do {                                                        \
        int t_ = __builtin_amdgcn_update_dpp(0, __builtin_bit_cast(int, x),       \
                                             (ctrl), 0xf, 0xf, false);            \
        x += __builtin_bit_cast(float, t_); } while (0)
    DPP_ADD(0x111);  // row_shr:1
    DPP_ADD(0x112);  // row_shr:2
    DPP_ADD(0x114);  // row_shr:4
    DPP_ADD(0x118);  // row_shr:8  -> lane 15/31/47/63 hold row sums
    DPP_ADD(0x142);  // row_bcast:15 -> lanes 31, 63 hold half sums
    DPP_ADD(0x143);  // row_bcast:31 -> lane 63 holds full sum
#undef DPP_ADD
    int s_ = __builtin_amdgcn_readlane(__builtin_bit_cast(int, x), 63);
    return __builtin_bit_cast(float, s_);
}

__device__ __forceinline__ float bcast_lane(float v, int l) {
    int r = __builtin_amdgcn_readlane(__builtin_bit_cast(int, v), l);
    return __builtin_bit_cast(float, r);
}

__global__ __launch_bounds__(NTHR, 2) void odenet_scan(
    const float* __restrict__ x,
    const float* __restrict__ W1, const float* __restrict__ b1,
    const float* __restrict__ W2, const float* __restrict__ b2,
    const float* __restrict__ W3, const float* __restrict__ b3,
    float* __restrict__ out) {

    const int b    = blockIdx.x;       // batch element
    const int tid  = threadIdx.x;
    const int s    = tid >> 7;         // k-split index 0..3 (wave-uniform)
    const int j    = tid & (HID - 1);  // hidden unit 0..127
    const int lane = tid & 63;

    __shared__ __align__(16) float h1buf[HID];
    __shared__ __align__(16) float pbuf[NTHR];   // layout [s*HID + j] (conflict-free)

    // ---- W2 fragment: rows [CHUNK*s, CHUNK*(s+1)) of column j, 32 scalars.
    // Resident across the loop (in AGPRs per R4 post-mortem; pins as insurance
    // against rematerialization-from-global across the barrier fences).
    const float* col = W2 + j;         // column j, row stride HID
    const int kb = CHUNK * s;
#define LW(k) col[(kb + (k)) * HID]
    float w00 = LW( 0), w01 = LW( 1), w02 = LW( 2), w03 = LW( 3);
    float w04 = LW( 4), w05 = LW( 5), w06 = LW( 6), w07 = LW( 7);
    float w08 = LW( 8), w09 = LW( 9), w10_ = LW(10), w11_ = LW(11);
    float w12 = LW(12), w13 = LW(13), w14 = LW(14), w15 = LW(15);
    float w16 = LW(16), w17 = LW(17), w18 = LW(18), w19 = LW(19);
    float w20 = LW(20), w21 = LW(21), w22 = LW(22), w23 = LW(23);
    float w24 = LW(24), w25 = LW(25), w26 = LW(26), w27 = LW(27);
    float w28 = LW(28), w29 = LW(29), w30 = LW(30), w31 = LW(31);
#undef LW
    float w10 = W1[j], w11 = W1[HID + j], b1j = b1[j];
    float b2a = b2[lane], b2b = b2[lane + 64];
    float w3a = W3[lane], w3b = W3[lane + 64];
    float b3v = b3[0];

#define PIN8(a,b_,c,d,e,f,g,h) asm volatile("" : "+v"(a),"+v"(b_),"+v"(c),      \
        "+v"(d),"+v"(e),"+v"(f),"+v"(g),"+v"(h))
    PIN8(w00, w01, w02, w03, w04, w05, w06, w07);
    PIN8(w08, w09, w10_, w11_, w12, w13, w14, w15);
    PIN8(w16, w17, w18, w19, w20, w21, w22, w23);
    PIN8(w24, w25, w26, w27, w28, w29, w30, w31);
    PIN8(w10, w11, b1j, b2a, b2b, w3a, w3b, b3v);
#undef PIN8

    float y    = 0.0f;
    float xbuf = 0.0f;   // waves 0-1: lane l holds x[(tblk+l)*B + b]
    float ybuf = 0.0f;   // waves 0-1: lane l holds y_{tblk+l+1}
    if (tid == 0) out[b] = 0.0f;       // y_0 = 0

    for (int t = 0; t < T_STEPS - 1; ++t) {
        const int tm = t & 63;
        // ---- phase A (waves 0-1): h1[j] = tanh(x*W1[0,j] + y*W1[1,j] + b1[j])
        if (s == 0) {
            if (tm == 0)                       // one 64-step x block per 64 steps
                xbuf = x[(t + lane) * BATCH + b];
            float xv = bcast_lane(xbuf, tm);   // uniform lane index (SGPR)
            h1buf[j] = fast_tanh(fmaf(xv, w10, fmaf(y, w11, b1j)));
        }
        __syncthreads();   // h1 ready; also orders prev C-reads before B-writes

        // ---- phase B (all 8 waves): partial dot, h1 via wave-uniform broadcast
        const float4* h4 = (const float4*)h1buf + s * (CHUNK / 4);
        float a0 = 0.f, a1 = 0.f, a2 = 0.f, a3 = 0.f;
        float4 h;
#define FMA4(wa, wb, wc, wd, idx) h = h4[idx];                                    \
        a0 = fmaf((wa), h.x, a0); a1 = fmaf((wb), h.y, a1);                       \
        a2 = fmaf((wc), h.z, a2); a3 = fmaf((wd), h.w, a3)
        FMA4(w00, w01, w02, w03, 0); FMA4(w04, w05, w06, w07, 1);
        FMA4(w08, w09, w10_, w11_, 2); FMA4(w12, w13, w14, w15, 3);
        FMA4(w16, w17, w18, w19, 4); FMA4(w20, w21, w22, w23, 5);
        FMA4(w24, w25, w26, w27, 6); FMA4(w28, w29, w30, w31, 7);
#undef FMA4
        pbuf[s * HID + j] = (a0 + a1) + (a2 + a3);
        __syncthreads();   // partials ready

        // ---- phase C (waves 0-1; both compute identical dy -> y replicated)
        if (s == 0) {
            float sa = pbuf[0 * HID + lane]      + pbuf[1 * HID + lane]
                     + pbuf[2 * HID + lane]      + pbuf[3 * HID + lane];
            float sb = pbuf[0 * HID + lane + 64] + pbuf[1 * HID + lane + 64]
                     + pbuf[2 * HID + lane + 64] + pbuf[3 * HID + lane + 64];
            float c = fmaf(w3a, fast_tanh(sa + b2a), w3b * fast_tanh(sb + b2b));
            y += wave64_sum(c) + b3v;               // DT = 1.0

            // capture y_{t+1} in lane tm (v_cndmask, no divergence)
            ybuf = (lane == tm) ? y : ybuf;
            // flush 64 states once per 64 steps (wave 0 only): y_{t-62..t+1}
            if (tm == 63 && tid < 64)
                out[(t - 62 + lane) * BATCH + b] = ybuf;
        }
    }
    // tail: steps t=8128..8190 captured y_8129..y_8191 in lanes 0..62 (wave 0)
    if (tid < 63)
        out[(T_STEPS - 63 + lane) * BATCH + b] = ybuf;
}

extern "C" void kernel_launch(void* const* d_in, const int* in_sizes, int n_in,
                              void* d_out, int out_size, void* d_ws, size_t ws_size,
                              hipStream_t stream) {
    const float* x  = (const float*)d_in[0];
    const float* W1 = (const float*)d_in[1];
    const float* b1 = (const float*)d_in[2];
    const float* W2 = (const float*)d_in[3];
    const float* b2 = (const float*)d_in[4];
    const float* W3 = (const float*)d_in[5];
    const float* b3 = (const float*)d_in[6];

    odenet_scan<<<dim3(BATCH), dim3(NTHR), 0, stream>>>(
        x, W1, b1, W2, b2, W3, b3, (float*)d_out);
}